// Round 1
// 127.574 us; speedup vs baseline: 1.0790x; 1.0790x over previous
//
#include <hip/hip_runtime.h>

// NCC loss, win=9, (1,1,160,192,224) fp32 -> scalar. Fully fused, round 10.
// R9 counters: VALU 29%, HBM 22%, occ 30%, conflicts 0 -> latency-bound, not
// roofline-bound. Diagnosis: per-thread state (ring 45 + pf 24 + temps ~= 105+
// values) overflows the reported 64 VGPRs into AGPRs (unified file) -> ~128
// regs/wave -> 16 waves/CU -> only TWO resident 512t blocks/CU. 54 block-wide
// barriers x 2 independent domains = exposed latency.
// R10: same 16 waves/CU but as FOUR independent 256t blocks:
//   - block 256t, TW=32 x TH=8, DCH=28 (ITERS=36=4x9, ring stays static)
//   - phases restructured to {H(i)} barA {W(i+1) || F(i)} barB so roles fit
//     256 threads: single SW (H reads in A, W writes in B), SH double-buffered
//     (F reads SH[i&1], H(i+1) writes SH[(i+1)&1]).
//   - LDS 45KB -> 21.8KB; grid 7x24x6=1008 ~= 3.94 blocks/CU (fills 4-cap).
// Barriers stay LDS-only (vmcnt unconstrained) so pf global loads span them.

#define DD 160
#define HH 192
#define WW 224
#define W4 56                 // WW/4
#define SLICE (HH * WW)
#define S4 (SLICE / 4)
#define NVOX (DD * SLICE)
#define TW 32
#define TH 8
#define DCH 28                // grid.z = 6 -> 1008 blocks
#define ITERS (DCH + 8)       // 36 = 4 * 9 (phase-static ring)
#define NTHR 256
#define SW_RS 36              // b128-aligned rows; 0-conflict pattern (R5/R7)
#define SW_CS (16 * SW_RS)    // 576 floats: 16 rows = TH + 8
#define SH_SZ (TH * TW * 5)   // 1280 floats
#define EPS 1e-5f
#define INV_WSUM (1.0f / 729.0f)

// Barrier that orders LDS only: s_waitcnt imm 0xC07F = lgkmcnt(0), vmcnt(63),
// expcnt(7) -> in-flight GLOBAL loads stay in flight across the barrier.
__device__ __forceinline__ void bar_lds_only() {
    __asm__ volatile("" ::: "memory");
    __builtin_amdgcn_s_waitcnt(0xC07F);
    __builtin_amdgcn_s_barrier();
    __asm__ volatile("" ::: "memory");
}

__global__ __launch_bounds__(NTHR, 4) void ncc_fused(const float* __restrict__ I,
                                                     const float* __restrict__ J,
                                                     float* __restrict__ out) {
    __shared__ float SW[5 * SW_CS];            // 11.52 KB, single buffer
    __shared__ float SH0[SH_SZ], SH1[SH_SZ];   // 5.12 KB each, double buffer
    __shared__ float wred[NTHR / 64];

    const int tid = threadIdx.x;
    const int tx = tid & 31, ty = tid >> 5;    // F mapping: 32 x 8
    const int wlo = blockIdx.x * TW;
    const int hlo = blockIdx.y * TH;
    const int dlo = blockIdx.z * DCH;

    // W-group (tid >= 128): 16 rows x 8 f4-col groups
    const int wid = tid - 128;
    const int wr = wid >> 3, wc = wid & 7;
    const int gh = hlo - 4 + wr;
    const bool hok = (gh >= 0) && (gh < HH);
    const int gf0 = (wlo >> 2) - 1 + wc;

    // H-group (tid < 160): 5 channels x 32 cols, 8 out-rows each (16 reads)
    const int hcol = tid & 31, hch = tid >> 5;

    const float4* Iv = (const float4*)I;
    const float4* Jv = (const float4*)J;

    // prefetch registers: one slice-row of raw I/J (12 floats each)
    float pfa[12], pfb[12];

    auto w_load = [&](int z) {   // fill pfa/pfb for slice z (zeros if OOB)
        const bool zok = (z >= 0) && (z < DD) && hok;
        const int rowb = z * S4 + gh * W4;
        #pragma unroll
        for (int k = 0; k < 3; ++k) {
            const int f = gf0 + k;
            float4 a = make_float4(0.f, 0.f, 0.f, 0.f);
            float4 b = make_float4(0.f, 0.f, 0.f, 0.f);
            if (zok && f >= 0 && f < W4) { a = Iv[rowb + f]; b = Jv[rowb + f]; }
            pfa[4*k] = a.x; pfa[4*k+1] = a.y; pfa[4*k+2] = a.z; pfa[4*k+3] = a.w;
            pfb[4*k] = b.x; pfb[4*k+1] = b.y; pfb[4*k+2] = b.z; pfb[4*k+3] = b.w;
        }
    };

    auto w_compute = [&]() {   // slide 9-tap W-sums from pfa/pfb -> SW
        float* wp = SW + wr * SW_RS + 4 * wc;
        #pragma unroll
        for (int ch = 0; ch < 5; ++ch) {
            float v[12];
            #pragma unroll
            for (int k = 0; k < 12; ++k)
                v[k] = (ch == 0) ? pfa[k]
                     : (ch == 1) ? pfb[k]
                     : (ch == 2) ? pfa[k] * pfa[k]
                     : (ch == 3) ? pfb[k] * pfb[k]
                     :             pfa[k] * pfb[k];
            float s = v[0];
            #pragma unroll
            for (int k = 1; k < 9; ++k) s += v[k];
            float4 o;
            o.x = s;
            s += v[9]  - v[0]; o.y = s;
            s += v[10] - v[1]; o.z = s;
            s += v[11] - v[2]; o.w = s;
            *(float4*)(wp + ch * SW_CS) = o;   // b128, 16B-aligned
        }
    };

    float q0[9], q1[9], q2[9], q3[9], q4[9];
    #pragma unroll
    for (int k = 0; k < 9; ++k) { q0[k]=0.f; q1[k]=0.f; q2[k]=0.f; q3[k]=0.f; q4[k]=0.f; }
    float r0=0.f, r1=0.f, r2=0.f, r3=0.f, r4=0.f;
    float acc = 0.f;

    // prologue: W(0) (slice dlo-4) -> SW; then prefetch slice dlo-3
    if (tid >= 128) {
        w_load(dlo - 4);
        if (dlo >= 4) w_compute();          // z0 < DD always (dlo <= 140)
        w_load(dlo - 3);
    }
    bar_lds_only();

    #pragma unroll 1
    for (int g = 0; g < 4; ++g) {
        #pragma unroll
        for (int ph = 0; ph < 9; ++ph) {
            const int i = 9 * g + ph;
            const int z = dlo - 4 + i;
            const bool val = (z >= 0) && (z < DD);   // block-uniform
            float* shW = (i & 1) ? SH1 : SH0;

            // ---- phase A: H(i): SW -> SH[i&1] ----
            if (tid < 160 && val) {
                const float* p = SW + hch * SW_CS + hcol;
                float v[16];
                #pragma unroll
                for (int r = 0; r < 16; r += 2) {   // pairs -> ds_read2_b32
                    const float* pr = p + r * SW_RS;
                    v[r]     = pr[0];
                    v[r + 1] = pr[SW_RS];
                }
                float s = v[0];
                #pragma unroll
                for (int r = 1; r < 9; ++r) s += v[r];
                float* o = shW + hcol * 5 + hch;    // [row][col][ch]
                float prev = s;
                o[0] = s;
                #pragma unroll
                for (int r = 1; r < TH; ++r) {
                    prev += v[r + 8] - v[r - 1];
                    o[r * (TW * 5)] = prev;
                }
            }
            bar_lds_only();   // barA: SH(i) visible to F; H done reading SW

            // ---- phase B: F(i) || W(i+1) ----
            float w0=0.f, w1=0.f, w2=0.f, w3=0.f, w4=0.f;
            if (val) {                               // issue F reads first
                const float* pF = shW + (ty * TW + tx) * 5;
                w0 = pF[0]; w1 = pF[1]; w2 = pF[2]; w3 = pF[3]; w4 = pF[4];
            }
            if (tid >= 128 && i < ITERS - 1) {
                const int zn = z + 1;
                if (zn >= 0 && zn < DD) w_compute();  // consume prefetch -> SW
                w_load(z + 2);                        // refill pf for i+1
            }
            r0 += w0 - q0[ph]; q0[ph] = w0;
            r1 += w1 - q1[ph]; q1[ph] = w1;
            r2 += w2 - q2[ph]; q2[ph] = w2;
            r3 += w3 - q3[ph]; q3[ph] = w3;
            r4 += w4 - q4[ph]; q4[ph] = w4;

            if (i >= 8 && (dlo + i - 8) < DD) {   // last chunk overhangs to 167
                float cross = r4 - r0 * r1 * INV_WSUM;
                float iv    = r2 - r0 * r0 * INV_WSUM;
                float jv    = r3 - r1 * r1 * INV_WSUM;
                acc += cross * cross * __builtin_amdgcn_rcpf(iv * jv + EPS);
            }
            bar_lds_only();   // barB: SW(i+1) visible to H(i+1); F done with SH
        }
    }

    // ---- block reduction -> one atomic (cold path: full __syncthreads ok) ----
    #pragma unroll
    for (int off = 32; off > 0; off >>= 1) acc += __shfl_down(acc, off, 64);
    if ((tid & 63) == 0) wred[tid >> 6] = acc;
    __syncthreads();
    if (tid == 0) {
        float t = 0.f;
        #pragma unroll
        for (int k = 0; k < NTHR / 64; ++k) t += wred[k];
        atomicAdd(out, t * (-1.0f / (float)NVOX));
    }
}

extern "C" void kernel_launch(void* const* d_in, const int* in_sizes, int n_in,
                              void* d_out, int out_size, void* d_ws, size_t ws_size,
                              hipStream_t stream) {
    const float* I = (const float*)d_in[0];
    const float* J = (const float*)d_in[1];
    float* out = (float*)d_out;

    hipMemsetAsync(d_out, 0, sizeof(float), stream);  // harness re-poisons d_out

    dim3 blk(NTHR, 1, 1);
    dim3 grd(WW / TW, HH / TH, (DD + DCH - 1) / DCH); // 7 x 24 x 6 = 1008 blocks
    ncc_fused<<<grd, blk, 0, stream>>>(I, J, out);
}